// Round 3
// baseline (369.439 us; speedup 1.0000x reference)
//
#include <hip/hip_runtime.h>

#define BB 128
#define CC 272
#define TT 1024
#define DD 270
#define KK 32
#define NKC 9              // K chunks of 32 (C padded to 288)
#define MP 272             // D padded to 17*16
#define WCH (MP * KK)      // ushorts per w chunk = 8704 (17 m-tiles x 512)
#define WBYTES (NKC * WCH * 2)   // 156,672 B total w buffer

typedef __attribute__((ext_vector_type(8))) short s16x8;
typedef __attribute__((ext_vector_type(4))) float f32x4;

__device__ __forceinline__ unsigned short f2bf(float f) {
  unsigned int u = __builtin_bit_cast(unsigned int, f);
  u += 0x7fffu + ((u >> 16) & 1u);   // round-to-nearest-even
  return (unsigned short)(u >> 16);
}

// ---------------- Kernel 1: partial A[d][c], 4-way k-split ----------------
__global__ __launch_bounds__(288) void phaseA_kernel(
    const float* __restrict__ loc, const float* __restrict__ z_re,
    const float* __restrict__ z_im, float* __restrict__ A) {
  const int d = blockIdx.x;
  const int p = blockIdx.y;          // k-part 0..3
  const int c = threadIdx.x;
  if (c >= CC) return;
  const float TWO_PI = 6.28318530717958647692f;
  float x = loc[2 * c], y = loc[2 * c + 1];
  float sx, cx, sy, cyv;
  sincosf(TWO_PI * x, &sx, &cx);
  sincosf(TWO_PI * y, &sy, &cyv);
  float cl[KK], sl[KK];
  cl[0] = 1.f; sl[0] = 0.f;
#pragma unroll
  for (int l = 1; l < KK; ++l) {
    cl[l] = cl[l - 1] * cyv - sl[l - 1] * sy;
    sl[l] = sl[l - 1] * cyv + cl[l - 1] * sy;
  }
  const int k0 = p * 8;
  float sk, ck;
  sincosf(TWO_PI * (float)k0 * x, &sk, &ck);
  const float* zr = z_re + (size_t)d * (KK * KK) + k0 * KK;
  const float* zi = z_im + (size_t)d * (KK * KK) + k0 * KK;
  float acc = 0.f;
  for (int k = 0; k < 8; ++k) {
    float s_rc = 0.f, s_rs = 0.f, s_ic = 0.f, s_is = 0.f;
#pragma unroll
    for (int l = 0; l < KK; ++l) {
      float vr = zr[k * KK + l];   // wave-uniform -> scalar loads
      float vi = zi[k * KK + l];
      s_rc += vr * cl[l];
      s_rs += vr * sl[l];
      s_ic += vi * cl[l];
      s_is += vi * sl[l];
    }
    acc += ck * (s_rc + s_is) + sk * (s_ic - s_rs);
    float nck = ck * cx - sk * sx;
    sk = sk * cx + ck * sx;
    ck = nck;
  }
  atomicAdd(&A[d * CC + c], acc);
}

// ---------------- Kernel 2: row softmax -> bf16 w, FRAGMENT-ORDER layout --
// ushort idx = kc*WCH + mt*512 + q*128 + r*8 + j
//   where d = mt*16 + r, kk = kc*32 + q*8 + j.
// In the gemm, lane (q*16+r) of any wave reads bytes [lane*16, lane*16+16)
// of the contiguous 1KB block (kc,mt) -> canonical conflict-free b128.
// Rows d>=270 and cols kk>=272 are zeros (M/K padding).
__global__ __launch_bounds__(64) void softmax_kernel(
    const float* __restrict__ A, unsigned short* __restrict__ wb) {
  const int d = blockIdx.x;   // 0..271
  const int lane = threadIdx.x;
  const bool live = (d < DD);
  float v[5];
  float inv = 0.f;
  if (live) {
    float m = -3.0e38f;
#pragma unroll
    for (int j = 0; j < 5; ++j) {
      int cidx = lane + 64 * j;
      v[j] = (cidx < CC) ? A[(size_t)d * CC + cidx] : -3.0e38f;
      m = fmaxf(m, v[j]);
    }
#pragma unroll
    for (int off = 32; off >= 1; off >>= 1) m = fmaxf(m, __shfl_xor(m, off, 64));
    float s = 0.f;
#pragma unroll
    for (int j = 0; j < 5; ++j) {
      int cidx = lane + 64 * j;
      v[j] = (cidx < CC) ? expf(v[j] - m) : 0.f;
      s += v[j];
    }
#pragma unroll
    for (int off = 32; off >= 1; off >>= 1) s += __shfl_xor(s, off, 64);
    inv = 1.f / s;
  }
  const int mt = d >> 4, r = d & 15;
#pragma unroll
  for (int j = 0; j < 5; ++j) {
    int kk = lane + 64 * j;
    if (kk < NKC * KK) {
      unsigned short val = 0;
      if (live && kk < CC) val = f2bf(v[j] * inv);
      int kc = kk >> 5, q = (kk >> 3) & 3, jj = kk & 7;
      wb[(size_t)kc * WCH + mt * 512 + q * 128 + r * 8 + jj] = val;
    }
  }
}

// ---------------- Kernel 3: out[b,d,t] = sum_c w[d,c] * X[b,c,t] ----------
// Grid = 256 = one persistent block per CU. Block: 1024 thr = 16 waves; wave
// owns a 16-t subtile; block covers 256 t, loops over 2 t-tiles (512 t total)
// reusing the once-staged w (all 9 chunks, fragment-ordered, conflict-free).
// Chunk-linear loop (18 chunks): prefetch depth 1 crosses the tile boundary,
// so tile-1 loads are in flight during tile-0's epilogue. No barriers after
// the initial staging sync.
__global__ __launch_bounds__(1024) void gemm_kernel(
    const float* __restrict__ X, const unsigned short* __restrict__ wb,
    float* __restrict__ out) {
  __shared__ unsigned short wlds[NKC * WCH];   // 156,672 B
  const int bid = blockIdx.x;
  const int b = bid >> 1;
  const int th = (bid & 1) * 512;    // t half: 0 or 512
  const int tid = threadIdx.x;
  const int lane = tid & 63;
  const int wv = tid >> 6;       // 0..15
  const int q = lane >> 4;       // quad 0..3
  const int r16 = lane & 15;
  const int csub = q * 8;        // c-offset within chunk for B-frag

  // ---- stage all of w: 9792 x 16B over 1024 threads (10 rounds) ----
  {
    const char* src = (const char*)wb;
    char* dst = (char*)wlds;
#pragma unroll
    for (int r = 0; r < 10; ++r) {
      int idx = tid + r * 1024;
      if (idx < WBYTES / 16) {
        __builtin_amdgcn_global_load_lds(
            (const __attribute__((address_space(1))) unsigned int*)(src + idx * 16),
            (__attribute__((address_space(3))) unsigned int*)(dst + idx * 16),
            16, 0, 0);
      }
    }
  }

  f32x4 acc[17];
#pragma unroll
  for (int i = 0; i < 17; ++i) acc[i] = (f32x4){0.f, 0.f, 0.f, 0.f};

  const float* Xb0 = X + (size_t)b * (CC * TT) + th + wv * 16 + r16;
  float* const ob0 = out + (size_t)b * (DD * TT) + th + wv * 16 + r16;

  float xf[8];
#pragma unroll
  for (int j = 0; j < 8; ++j) xf[j] = Xb0[(size_t)(csub + j) * TT];  // chunk 0

  __syncthreads();   // w fully in LDS (vmcnt(0)). The only barrier.

  for (int cl = 0; cl < 18; ++cl) {
    const int kc = cl - (cl >= 9 ? 9 : 0);
    if (cl == 9) {
      // epilogue tile 0 (tile-1 chunk-0 loads already in flight)
      float* op = ob0;
#pragma unroll
      for (int mt = 0; mt < 17; ++mt) {
#pragma unroll
        for (int r = 0; r < 4; ++r) {
          int drow = mt * 16 + q * 4 + r;
          if (drow < DD) op[(size_t)drow * TT] = acc[mt][r];
        }
      }
#pragma unroll
      for (int i = 0; i < 17; ++i) acc[i] = (f32x4){0.f, 0.f, 0.f, 0.f};
    }
    // prefetch next linear chunk
    float xn[8];
    if (cl < 17) {
      const int nl = cl + 1;
      const int nkc = nl - (nl >= 9 ? 9 : 0);
      const float* Xb = Xb0 + (nl >= 9 ? 256 : 0);
      const int cb = nkc * KK + csub;
      if (nkc == 8 && csub >= 16) {        // c in [272,288): K padding
#pragma unroll
        for (int j = 0; j < 8; ++j) xn[j] = 0.f;
      } else {
#pragma unroll
        for (int j = 0; j < 8; ++j) xn[j] = Xb[(size_t)(cb + j) * TT];
      }
    } else {
#pragma unroll
      for (int j = 0; j < 8; ++j) xn[j] = 0.f;
    }
    // pack current B-frag (waits vmcnt(8): only the previous chunk's loads)
    union { unsigned int u[4]; s16x8 v; } bf;
#pragma unroll
    for (int j2 = 0; j2 < 4; ++j2)
      bf.u[j2] = (unsigned int)f2bf(xf[2 * j2]) |
                 ((unsigned int)f2bf(xf[2 * j2 + 1]) << 16);
    const char* wchunk = (const char*)wlds + kc * (WCH * 2);
#pragma unroll
    for (int mt = 0; mt < 17; ++mt) {
      s16x8 afrag = *(const s16x8*)(wchunk + mt * 1024 + lane * 16);
      acc[mt] = __builtin_amdgcn_mfma_f32_16x16x32_bf16(afrag, bf.v, acc[mt], 0, 0, 0);
    }
#pragma unroll
    for (int j = 0; j < 8; ++j) xf[j] = xn[j];
  }

  // epilogue tile 1
  float* op = ob0 + 256;
#pragma unroll
  for (int mt = 0; mt < 17; ++mt) {
#pragma unroll
    for (int r = 0; r < 4; ++r) {
      int drow = mt * 16 + q * 4 + r;
      if (drow < DD) op[(size_t)drow * TT] = acc[mt][r];
    }
  }
}

extern "C" void kernel_launch(void* const* d_in, const int* in_sizes, int n_in,
                              void* d_out, int out_size, void* d_ws, size_t ws_size,
                              hipStream_t stream) {
  const float* X = (const float*)d_in[0];
  const float* loc = (const float*)d_in[1];
  const float* z_re = (const float*)d_in[2];
  const float* z_im = (const float*)d_in[3];
  float* out = (float*)d_out;

  float* A = (float*)d_ws;                                        // 293,760 B
  unsigned short* wbf = (unsigned short*)((char*)d_ws + 294912);  // 156,672 B

  hipMemsetAsync(A, 0, DD * CC * sizeof(float), stream);
  phaseA_kernel<<<dim3(DD, 4), 288, 0, stream>>>(loc, z_re, z_im, A);
  softmax_kernel<<<MP, 64, 0, stream>>>(A, wbf);
  gemm_kernel<<<BB * 2, 1024, 0, stream>>>(X, wbf, out);
}